// Round 2
// baseline (329.269 us; speedup 1.0000x reference)
//
#include <hip/hip_runtime.h>
#include <math.h>

// SSIM-with-logits fused kernel for MI355X (gfx950). Round 6.
// R5 post-mortem: TILE_H=64 + single buffer raised VGPR 112->128 with 31 MB
// scratch-spill writes (the 44-reg deep prefetch + 55-reg accumulators don't
// fit a high-occupancy budget); occupancy stayed 19%, dur 90->103 us.
// R6 keeps the 4-blocks/CU goal but deletes the deep prefetch entirely:
//  - stage rows global->LDS row-by-row (unroll 2, ~8 loads in flight);
//    latency hidden by cross-block TLP (4 blocks/CU), not per-wave depth
//  - __launch_bounds__(256,4): 128-VGPR budget; live state now ~100 VGPR
//    (56 accum + temps) -> no spill (falsifiable via WRITE_SIZE)
//  - vX vertical taps packed into f2 slot-pairs: 11 fma -> 6 pk_fma,
//    compile-time weight pairs, bit-exact per lane

typedef __attribute__((ext_vector_type(2))) float f2;

#define H_IMG 1024
#define W_IMG 1024
#define N_IMG 16
#define TILE_W 256
#define TILE_H 64
#define PADR 5
#define LDS_S2 268  // f2 cells per staged row (>= 266)

// Normalized 1D Gaussian, WS=11, sigma=1.5 (absmax 0.0 in R1-R5)
constexpr float GW[11] = {
    0.00102838f, 0.00759877f, 0.03600077f, 0.10936069f, 0.21300553f,
    0.26601172f,
    0.21300553f, 0.10936069f, 0.03600077f, 0.00759877f, 0.00102838f};

__device__ __forceinline__ int reflect_i(int i, int n) {
    i = (i < 0) ? -i : i;
    i = (i >= n) ? (2 * n - 2 - i) : i;
    return i;
}

__device__ __forceinline__ float fast_sigmoid(float x) {
    return __builtin_amdgcn_rcpf(1.0f + __expf(-x));
}

__device__ __forceinline__ void ssim_emit(
    f2 mu, f2 sq, float e12, float& loss_sum)
{
    const float mu1 = mu.x, mu2 = mu.y;
    const float mu1s = mu1 * mu1;
    const float mu2s = mu2 * mu2;
    const float mu12 = mu1 * mu2;
    const float s1  = sq.x - mu1s;
    const float s2  = sq.y - mu2s;
    const float s12 = e12  - mu12;
    const float C1 = 1e-4f, C2 = 9e-4f;
    const float num = (2.0f * mu12 + C1) * (2.0f * s12 + C2);
    const float den = (mu1s + mu2s + C1) * (s1 + s2 + C2);
    float l = 1.0f - num * __builtin_amdgcn_rcpf(den);
    l = fminf(fmaxf(l, 0.0f), 1.0f) * 0.5f;
    loss_sum += l;
}

// Stage NR rows of the group at base gb: global -> (sigmoid) -> LDS.
// No deep prefetch: unroll 2 keeps ~8 loads in flight, TLP does the rest.
template<int NR>
__device__ __forceinline__ void stage_group(
    const float* __restrict__ A, const float* __restrict__ B,
    int y_start, int gb, int c0, int c1, int tid,
    f2 (*__restrict__ buf)[LDS_S2])
{
#pragma unroll 2
    for (int r = 0; r < NR; ++r) {
        const int yy = reflect_i(y_start + gb + r, H_IMG);
        const size_t ro = (size_t)yy << 10;   // *W_IMG (1024)
        const float a0 = A[ro + c0];
        const float b0 = B[ro + c0];
        float a1 = 0.0f, b1 = 0.0f;
        const bool halo = (tid < 2 * PADR);
        if (halo) {
            a1 = A[ro + c1];
            b1 = B[ro + c1];
        }
        buf[r][tid] = (f2){fast_sigmoid(a0), b0};
        if (halo)
            buf[r][TILE_W + tid] = (f2){fast_sigmoid(a1), b1};
    }
}

// Process NR staged rows from `buf`. Group base must be == 0 mod 11 so the
// mod-11 slot indices fold to compile-time constants (validated R2-R5,
// absmax 0.0). GUARD: first group (edge); invalid taps get compile-time
// zero weights (0*finite = +0, exact), only r==10 completes an output.
template<int NR, bool GUARD>
__device__ __forceinline__ void process_group(
    const f2 (*__restrict__ buf)[LDS_S2], int tid,
    f2 (&vAB)[11], f2 (&vSQ)[11], f2 (&vXp)[6], float& loss_sum)
{
#pragma unroll
    for (int r = 0; r < NR; ++r) {
        // ---- horizontal 11-tap, packed (a,b)/(aa,bb) + scalar ab ----
        f2 hAB = (f2)(0.0f), hSQ = (f2)(0.0f);
        float hab = 0.0f;
#pragma unroll
        for (int k = 0; k < 11; ++k) {
            const f2 v   = buf[r][tid + k];
            const f2 wa2 = ((f2)(GW[k])) * v;         // (GW*a, GW*b)
            hAB += wa2;
            hSQ  = __builtin_elementwise_fma(wa2, v, hSQ);
            hab  = fmaf(wa2.x, v.y, hab);
        }
        // ---- vertical scatter, channel-packed (a,b) and (aa,bb) ----
#pragma unroll
        for (int j = 0; j < 11; ++j) {
            if (!(GUARD && j > r)) {
                const int s = (r - j + 22) % 11;
                const f2 w2 = (f2)(GW[j]);
                vAB[s] = __builtin_elementwise_fma(w2, hAB, vAB[s]);
                vSQ[s] = __builtin_elementwise_fma(w2, hSQ, vSQ[s]);
            }
        }
        // ---- vertical scatter for ab, slot-PAIR packed: 6 pk_fma ----
#pragma unroll
        for (int p = 0; p < 6; ++p) {
            const int s0 = 2 * p, s1 = 2 * p + 1;
            const int j0 = (r - s0 + 22) % 11;
            const int j1 = (s1 <= 10) ? ((r - s1 + 22) % 11) : 0;
            float w0 = GW[j0];
            float w1 = (s1 <= 10) ? GW[j1] : 0.0f;
            if (GUARD && j0 > r) w0 = 0.0f;
            if (GUARD && (s1 > 10 || j1 > r)) w1 = 0.0f;
            if (w0 != 0.0f || w1 != 0.0f)
                vXp[p] = __builtin_elementwise_fma(
                    (f2){w0, w1}, (f2){hab, hab}, vXp[p]);
        }
        // ---- completion: slot (r+1)%11 finished an output row ----
        if (!GUARD || r == 10) {
            const int s = (r + 1) % 11;
            const float e12 = (s & 1) ? vXp[s >> 1].y : vXp[s >> 1].x;
            ssim_emit(vAB[s], vSQ[s], e12, loss_sum);
            vAB[s] = (f2)(0.0f); vSQ[s] = (f2)(0.0f);
            if (s & 1) vXp[s >> 1].y = 0.0f; else vXp[s >> 1].x = 0.0f;
        }
    }
}

__global__ __launch_bounds__(256, 4) void ssim_main(
    const float* __restrict__ inp, const float* __restrict__ tgt,
    float* __restrict__ out)
{
    __shared__ f2 buf[11][LDS_S2];   // single buffer, ~23.6 KB -> 4 blocks/CU
    __shared__ float red[4];

    const int tid = threadIdx.x;
    const int blk = blockIdx.x;
    const int b   = blk >> 6;           // image 0..15 (64 blocks/image)
    const int rem = blk & 63;
    const int cx  = rem & 3;            // column tile 0..3
    const int ry  = rem >> 2;           // row band 0..15
    const int x0  = cx * TILE_W;
    const int y0  = ry * TILE_H;

    const float* __restrict__ A = inp + (size_t)b * (H_IMG * (size_t)W_IMG);
    const float* __restrict__ B = tgt + (size_t)b * (H_IMG * (size_t)W_IMG);

    const int c0 = reflect_i(x0 - PADR + tid, W_IMG);
    const int c1 = (tid < 2 * PADR) ? reflect_i(x0 + TILE_W - PADR + tid, W_IMG) : 0;

    f2 vAB[11], vSQ[11], vXp[6];
#pragma unroll
    for (int j = 0; j < 11; ++j) {
        vAB[j] = (f2)(0.0f); vSQ[j] = (f2)(0.0f);
    }
#pragma unroll
    for (int p = 0; p < 6; ++p) vXp[p] = (f2)(0.0f);
    float loss_sum = 0.0f;

    const int y_start = y0 - PADR;  // 74 input rows: 6 groups of 11 + 8

    // group 0 (edge-guarded)
    stage_group<11>(A, B, y_start, 0, c0, c1, tid, buf);
    __syncthreads();
    process_group<11, true>(buf, tid, vAB, vSQ, vXp, loss_sum);

    // groups 1..5: WAR barrier, stage, RAW barrier, process.
    // Stage latency is covered by the other 3 resident blocks on the CU.
#pragma unroll 1
    for (int g = 1; g <= 5; ++g) {
        __syncthreads();                 // all waves done reading buf
        stage_group<11>(A, B, y_start, g * 11, c0, c1, tid, buf);
        __syncthreads();                 // writes visible
        process_group<11, false>(buf, tid, vAB, vSQ, vXp, loss_sum);
    }

    // tail: group 6, rows 66..73 (66 % 11 == 0)
    __syncthreads();
    stage_group<8>(A, B, y_start, 66, c0, c1, tid, buf);
    __syncthreads();
    process_group<8, false>(buf, tid, vAB, vSQ, vXp, loss_sum);

    // ---- reduction: wave64 shuffle -> LDS across 4 waves -> atomicAdd ----
#pragma unroll
    for (int off = 32; off > 0; off >>= 1)
        loss_sum += __shfl_down(loss_sum, off, 64);
    const int wave = tid >> 6;
    if ((tid & 63) == 0) red[wave] = loss_sum;
    __syncthreads();
    if (tid == 0) {
        const float s = red[0] + red[1] + red[2] + red[3];
        atomicAdd(out, s * (1.0f / ((float)N_IMG * H_IMG * W_IMG)));
    }
}

extern "C" void kernel_launch(void* const* d_in, const int* in_sizes, int n_in,
                              void* d_out, int out_size, void* d_ws, size_t ws_size,
                              hipStream_t stream) {
    const float* inp = (const float*)d_in[0];
    const float* tgt = (const float*)d_in[1];
    float* out = (float*)d_out;

    // d_out is poisoned 0xAA before every launch; zero it for the atomic sum.
    hipMemsetAsync(out, 0, sizeof(float), stream);

    const int grid = N_IMG * 4 * (H_IMG / TILE_H);  // 1024 blocks, 4/CU
    ssim_main<<<grid, 256, 0, stream>>>(inp, tgt, out);
}

// Round 3
// 275.802 us; speedup vs baseline: 1.1939x; 1.1939x over previous
//
#include <hip/hip_runtime.h>
#include <math.h>

// SSIM-with-logits fused kernel for MI355X (gfx950). Round 7.
// R6 post-mortem: __launch_bounds__(256,4) made the allocator target a
// 64-VGPR budget -> 212 MB scratch spill, dur 237 us. Rule confirmed
// across R3/R5/R6: ANY bound tighter than (256,2) spills this kernel.
// R7 = R6 structure with the proven spill-free (256,2) bound. Occupancy
// comes from ACTUAL usage: live state is ~56 accum floats + temps
// (~110 VGPR) -> 4 waves/SIMD -> 4 blocks/CU; LDS 24 KB allows 6, so
// VGPR is the (intentional, non-binding-on-spill) limiter.
//  - stage rows global->LDS row-by-row (unroll 2, ~8 loads in flight);
//    latency hidden by cross-block TLP, not per-wave depth
//  - single LDS buffer, 2 barriers/group
//  - vX vertical taps packed into f2 slot-pairs (6 pk_fma, bit-exact)

typedef __attribute__((ext_vector_type(2))) float f2;

#define H_IMG 1024
#define W_IMG 1024
#define N_IMG 16
#define TILE_W 256
#define TILE_H 64
#define PADR 5
#define LDS_S2 268  // f2 cells per staged row (>= 266)

// Normalized 1D Gaussian, WS=11, sigma=1.5 (absmax 0.0 in R1-R6)
constexpr float GW[11] = {
    0.00102838f, 0.00759877f, 0.03600077f, 0.10936069f, 0.21300553f,
    0.26601172f,
    0.21300553f, 0.10936069f, 0.03600077f, 0.00759877f, 0.00102838f};

__device__ __forceinline__ int reflect_i(int i, int n) {
    i = (i < 0) ? -i : i;
    i = (i >= n) ? (2 * n - 2 - i) : i;
    return i;
}

__device__ __forceinline__ float fast_sigmoid(float x) {
    return __builtin_amdgcn_rcpf(1.0f + __expf(-x));
}

__device__ __forceinline__ void ssim_emit(
    f2 mu, f2 sq, float e12, float& loss_sum)
{
    const float mu1 = mu.x, mu2 = mu.y;
    const float mu1s = mu1 * mu1;
    const float mu2s = mu2 * mu2;
    const float mu12 = mu1 * mu2;
    const float s1  = sq.x - mu1s;
    const float s2  = sq.y - mu2s;
    const float s12 = e12  - mu12;
    const float C1 = 1e-4f, C2 = 9e-4f;
    const float num = (2.0f * mu12 + C1) * (2.0f * s12 + C2);
    const float den = (mu1s + mu2s + C1) * (s1 + s2 + C2);
    float l = 1.0f - num * __builtin_amdgcn_rcpf(den);
    l = fminf(fmaxf(l, 0.0f), 1.0f) * 0.5f;
    loss_sum += l;
}

// Stage NR rows of the group at base gb: global -> (sigmoid) -> LDS.
// No deep prefetch: unroll 2 keeps ~8 loads in flight, TLP does the rest.
template<int NR>
__device__ __forceinline__ void stage_group(
    const float* __restrict__ A, const float* __restrict__ B,
    int y_start, int gb, int c0, int c1, int tid,
    f2 (*__restrict__ buf)[LDS_S2])
{
#pragma unroll 2
    for (int r = 0; r < NR; ++r) {
        const int yy = reflect_i(y_start + gb + r, H_IMG);
        const size_t ro = (size_t)yy << 10;   // *W_IMG (1024)
        const float a0 = A[ro + c0];
        const float b0 = B[ro + c0];
        float a1 = 0.0f, b1 = 0.0f;
        const bool halo = (tid < 2 * PADR);
        if (halo) {
            a1 = A[ro + c1];
            b1 = B[ro + c1];
        }
        buf[r][tid] = (f2){fast_sigmoid(a0), b0};
        if (halo)
            buf[r][TILE_W + tid] = (f2){fast_sigmoid(a1), b1};
    }
}

// Process NR staged rows from `buf`. Group base must be == 0 mod 11 so the
// mod-11 slot indices fold to compile-time constants (validated R2-R6,
// absmax 0.0). GUARD: first group (edge); invalid taps get compile-time
// zero weights (0*finite = +0, exact), only r==10 completes an output.
template<int NR, bool GUARD>
__device__ __forceinline__ void process_group(
    const f2 (*__restrict__ buf)[LDS_S2], int tid,
    f2 (&vAB)[11], f2 (&vSQ)[11], f2 (&vXp)[6], float& loss_sum)
{
#pragma unroll
    for (int r = 0; r < NR; ++r) {
        // ---- horizontal 11-tap, packed (a,b)/(aa,bb) + scalar ab ----
        f2 hAB = (f2)(0.0f), hSQ = (f2)(0.0f);
        float hab = 0.0f;
#pragma unroll
        for (int k = 0; k < 11; ++k) {
            const f2 v   = buf[r][tid + k];
            const f2 wa2 = ((f2)(GW[k])) * v;         // (GW*a, GW*b)
            hAB += wa2;
            hSQ  = __builtin_elementwise_fma(wa2, v, hSQ);
            hab  = fmaf(wa2.x, v.y, hab);
        }
        // ---- vertical scatter, channel-packed (a,b) and (aa,bb) ----
#pragma unroll
        for (int j = 0; j < 11; ++j) {
            if (!(GUARD && j > r)) {
                const int s = (r - j + 22) % 11;
                const f2 w2 = (f2)(GW[j]);
                vAB[s] = __builtin_elementwise_fma(w2, hAB, vAB[s]);
                vSQ[s] = __builtin_elementwise_fma(w2, hSQ, vSQ[s]);
            }
        }
        // ---- vertical scatter for ab, slot-PAIR packed: 6 pk_fma ----
#pragma unroll
        for (int p = 0; p < 6; ++p) {
            const int s0 = 2 * p, s1 = 2 * p + 1;
            const int j0 = (r - s0 + 22) % 11;
            const int j1 = (s1 <= 10) ? ((r - s1 + 22) % 11) : 0;
            float w0 = GW[j0];
            float w1 = (s1 <= 10) ? GW[j1] : 0.0f;
            if (GUARD && j0 > r) w0 = 0.0f;
            if (GUARD && (s1 > 10 || j1 > r)) w1 = 0.0f;
            if (w0 != 0.0f || w1 != 0.0f)
                vXp[p] = __builtin_elementwise_fma(
                    (f2){w0, w1}, (f2){hab, hab}, vXp[p]);
        }
        // ---- completion: slot (r+1)%11 finished an output row ----
        if (!GUARD || r == 10) {
            const int s = (r + 1) % 11;
            const float e12 = (s & 1) ? vXp[s >> 1].y : vXp[s >> 1].x;
            ssim_emit(vAB[s], vSQ[s], e12, loss_sum);
            vAB[s] = (f2)(0.0f); vSQ[s] = (f2)(0.0f);
            if (s & 1) vXp[s >> 1].y = 0.0f; else vXp[s >> 1].x = 0.0f;
        }
    }
}

__global__ __launch_bounds__(256, 2) void ssim_main(
    const float* __restrict__ inp, const float* __restrict__ tgt,
    float* __restrict__ out)
{
    __shared__ f2 buf[11][LDS_S2];   // single buffer, ~23.6 KB
    __shared__ float red[4];

    const int tid = threadIdx.x;
    const int blk = blockIdx.x;
    const int b   = blk >> 6;           // image 0..15 (64 blocks/image)
    const int rem = blk & 63;
    const int cx  = rem & 3;            // column tile 0..3
    const int ry  = rem >> 2;           // row band 0..15
    const int x0  = cx * TILE_W;
    const int y0  = ry * TILE_H;

    const float* __restrict__ A = inp + (size_t)b * (H_IMG * (size_t)W_IMG);
    const float* __restrict__ B = tgt + (size_t)b * (H_IMG * (size_t)W_IMG);

    const int c0 = reflect_i(x0 - PADR + tid, W_IMG);
    const int c1 = (tid < 2 * PADR) ? reflect_i(x0 + TILE_W - PADR + tid, W_IMG) : 0;

    f2 vAB[11], vSQ[11], vXp[6];
#pragma unroll
    for (int j = 0; j < 11; ++j) {
        vAB[j] = (f2)(0.0f); vSQ[j] = (f2)(0.0f);
    }
#pragma unroll
    for (int p = 0; p < 6; ++p) vXp[p] = (f2)(0.0f);
    float loss_sum = 0.0f;

    const int y_start = y0 - PADR;  // 74 input rows: 6 groups of 11 + 8

    // group 0 (edge-guarded)
    stage_group<11>(A, B, y_start, 0, c0, c1, tid, buf);
    __syncthreads();
    process_group<11, true>(buf, tid, vAB, vSQ, vXp, loss_sum);

    // groups 1..5: WAR barrier, stage, RAW barrier, process.
    // Stage latency covered by the other resident blocks on the CU.
#pragma unroll 1
    for (int g = 1; g <= 5; ++g) {
        __syncthreads();                 // all waves done reading buf
        stage_group<11>(A, B, y_start, g * 11, c0, c1, tid, buf);
        __syncthreads();                 // writes visible
        process_group<11, false>(buf, tid, vAB, vSQ, vXp, loss_sum);
    }

    // tail: group 6, rows 66..73 (66 % 11 == 0)
    __syncthreads();
    stage_group<8>(A, B, y_start, 66, c0, c1, tid, buf);
    __syncthreads();
    process_group<8, false>(buf, tid, vAB, vSQ, vXp, loss_sum);

    // ---- reduction: wave64 shuffle -> LDS across 4 waves -> atomicAdd ----
#pragma unroll
    for (int off = 32; off > 0; off >>= 1)
        loss_sum += __shfl_down(loss_sum, off, 64);
    const int wave = tid >> 6;
    if ((tid & 63) == 0) red[wave] = loss_sum;
    __syncthreads();
    if (tid == 0) {
        const float s = red[0] + red[1] + red[2] + red[3];
        atomicAdd(out, s * (1.0f / ((float)N_IMG * H_IMG * W_IMG)));
    }
}

extern "C" void kernel_launch(void* const* d_in, const int* in_sizes, int n_in,
                              void* d_out, int out_size, void* d_ws, size_t ws_size,
                              hipStream_t stream) {
    const float* inp = (const float*)d_in[0];
    const float* tgt = (const float*)d_in[1];
    float* out = (float*)d_out;

    // d_out is poisoned 0xAA before every launch; zero it for the atomic sum.
    hipMemsetAsync(out, 0, sizeof(float), stream);

    const int grid = N_IMG * 4 * (H_IMG / TILE_H);  // 1024 blocks
    ssim_main<<<grid, 256, 0, stream>>>(inp, tgt, out);
}